// Round 1
// baseline (496.791 us; speedup 1.0000x reference)
//
#include <hip/hip_runtime.h>
#include <hip/hip_bf16.h>
#include <cstdint>
#include <cstddef>

// ---------------- problem constants ----------------
#define TOKENS   8192          // B*S
#define HID      2048
#define LAT      512
#define LAT2     1024
#define GCOLS    2048          // 4 gates * LAT (packed col = 4*l + g)
#define STEPS    8
#define DEC_ELEMS (TOKENS*HID)

typedef __attribute__((ext_vector_type(8))) __bf16 bf16x8;
typedef __attribute__((ext_vector_type(4))) float  f32x4;

// ---------------- helpers ----------------
__device__ __forceinline__ unsigned short f32_to_bf16_rne(float f) {
  unsigned int u = __float_as_uint(f);
  unsigned int r = (u + 0x7FFFu + ((u >> 16) & 1u)) >> 16;
  return (unsigned short)r;
}

__device__ __forceinline__ float sigmoidf_(float x) {
  if (x >= 0.f) { float e = __expf(-x); return 1.f / (1.f + e); }
  float e = __expf(x); return e / (1.f + e);
}
__device__ __forceinline__ float tanhf_(float x) {
  float ax = fabsf(x);
  float e  = __expf(-2.f * ax);
  float t  = (1.f - e) / (1.f + e);
  return copysignf(t, x);
}

__device__ __forceinline__ void gl_lds16(const void* g, void* l) {
  __builtin_amdgcn_global_load_lds(
      (const __attribute__((address_space(1))) void*)g,
      (__attribute__((address_space(3))) void*)l, 16, 0, 0);
}

// ---------------- prep kernels ----------------
__global__ void k_cast(const float* __restrict__ s, unsigned short* __restrict__ d, int n4) {
  int i = blockIdx.x * blockDim.x + threadIdx.x;
  int stride = gridDim.x * blockDim.x;
  for (; i < n4; i += stride) {
    float4 v = ((const float4*)s)[i];
    ushort4 o;
    o.x = f32_to_bf16_rne(v.x);
    o.y = f32_to_bf16_rne(v.y);
    o.z = f32_to_bf16_rne(v.z);
    o.w = f32_to_bf16_rne(v.w);
    ((ushort4*)d)[i] = o;
  }
}

// Pack GRU weights: output row gc = 4*l + g, g in {0:r-sum, 1:z-sum, 2:i_n, 3:h_n}
__global__ void k_gru_pack(const float* __restrict__ wih, const float* __restrict__ whh,
                           const float* __restrict__ bih, const float* __restrict__ bhh,
                           unsigned short* __restrict__ Wg, float* __restrict__ biasg) {
  int gc = blockIdx.x;            // 0..2047
  int l  = gc >> 2;
  int g  = gc & 3;
  int row = (g == 0) ? l : (g == 1) ? (512 + l) : (1024 + l);
  for (int c = threadIdx.x; c < LAT; c += blockDim.x) {
    float v;
    if (g <= 1)      v = wih[row * LAT + c] + whh[row * LAT + c];
    else if (g == 2) v = wih[row * LAT + c];
    else             v = whh[row * LAT + c];
    Wg[(size_t)gc * LAT + c] = f32_to_bf16_rne(v);
  }
  if (threadIdx.x == 0) {
    float b;
    if (g <= 1)      b = bih[row] + bhh[row];
    else if (g == 2) b = bih[row];
    else             b = bhh[row];
    biasg[gc] = b;
  }
}

// ---------------- main GEMM: C[M,N] = A[M,K] * W[N,K]^T, fused epilogues ----------------
// EPI 0: out_b = bf16(relu(acc+bias))
// EPI 1: out_f = acc+bias ; out_b = bf16(same)          (latent after encode)
// EPI 2: out_f = acc+bias                               (decoded -> d_out)
// EPI 3: GRU gate epilogue (bias=packed biasg, hIn=Lf_in, writes Lf/Lb out + traj)
#define MWG 128
#define NWG 128
#define KTILE 64

template <int EPI>
__global__ __launch_bounds__(256)
void gemm_bt(const unsigned short* __restrict__ A,   // [M x K] bf16 bits
             const unsigned short* __restrict__ W,   // [N x K] bf16 bits
             const float* __restrict__ bias,         // [N]
             int K, int N,
             float* __restrict__ outF,
             unsigned short* __restrict__ outB,
             const float* __restrict__ hIn,
             float* __restrict__ traj,
             int step) {
  __shared__ __align__(16) char smem[2 * MWG * KTILE * 2];   // 32 KiB
  unsigned short* As = (unsigned short*)smem;
  unsigned short* Bs = As + MWG * KTILE;

  const int tid  = threadIdx.x;
  const int lane = tid & 63;
  const int wv   = tid >> 6;        // 4 waves
  const int wr   = wv >> 1;         // 0/1
  const int wc   = wv & 1;          // 0/1
  const int m0   = blockIdx.x * MWG;
  const int n0   = blockIdx.y * NWG;

  const int lr = lane & 15;         // fragment row (A) / col (B/D)
  const int lq = lane >> 4;         // k-group 0..3

  const int srow = lane >> 3;       // staging: row within 8-row chunk
  const int scol = (lane & 7) * 8;  // staging: element col

  f32x4 acc[4][4];
#pragma unroll
  for (int i = 0; i < 4; ++i)
#pragma unroll
    for (int j = 0; j < 4; ++j) acc[i][j] = (f32x4){0.f, 0.f, 0.f, 0.f};

  const unsigned short* Ab = A + (size_t)m0 * K;
  const unsigned short* Wb = W + (size_t)n0 * K;

  const int KT = K / KTILE;
  for (int kt = 0; kt < KT; ++kt) {
    const int k0 = kt * KTILE;
    // stage A & B tiles: each wave moves 32 rows of each via 4+4 global_load_lds
#pragma unroll
    for (int q = 0; q < 4; ++q) {
      int row = 32 * wv + 8 * q + srow;
      gl_lds16(Ab + (size_t)row * K + k0 + scol, As + (32 * wv + 8 * q) * KTILE);
      gl_lds16(Wb + (size_t)row * K + k0 + scol, Bs + (32 * wv + 8 * q) * KTILE);
    }
    __syncthreads();
#pragma unroll
    for (int kk = 0; kk < KTILE; kk += 32) {
      bf16x8 af[4], bf[4];
#pragma unroll
      for (int i = 0; i < 4; ++i)
        af[i] = *(const bf16x8*)(As + (wr * 64 + i * 16 + lr) * KTILE + kk + lq * 8);
#pragma unroll
      for (int j = 0; j < 4; ++j)
        bf[j] = *(const bf16x8*)(Bs + (wc * 64 + j * 16 + lr) * KTILE + kk + lq * 8);
#pragma unroll
      for (int i = 0; i < 4; ++i)
#pragma unroll
        for (int j = 0; j < 4; ++j)
          acc[i][j] = __builtin_amdgcn_mfma_f32_16x16x32_bf16(af[i], bf[j], acc[i][j], 0, 0, 0);
    }
    __syncthreads();
  }

  // -------- epilogues --------
  if constexpr (EPI == 0 || EPI == 1 || EPI == 2) {
    float bj[4];
#pragma unroll
    for (int j = 0; j < 4; ++j) bj[j] = bias[n0 + wc * 64 + j * 16 + lr];
#pragma unroll
    for (int i = 0; i < 4; ++i) {
#pragma unroll
      for (int ii = 0; ii < 4; ++ii) {
        int row = m0 + wr * 64 + i * 16 + 4 * lq + ii;
#pragma unroll
        for (int j = 0; j < 4; ++j) {
          int col = n0 + wc * 64 + j * 16 + lr;
          float v = acc[i][j][ii] + bj[j];
          if constexpr (EPI == 0) {
            v = fmaxf(v, 0.f);
            outB[(size_t)row * N + col] = f32_to_bf16_rne(v);
          } else if constexpr (EPI == 1) {
            outF[(size_t)row * N + col] = v;
            outB[(size_t)row * N + col] = f32_to_bf16_rne(v);
          } else {
            outF[(size_t)row * N + col] = v;
          }
        }
      }
    }
  } else {
    // GRU: wave tile = 64 tokens x 64 gate-cols = 16 latent dims (col = 4*l + g)
    float bj[4];
#pragma unroll
    for (int j = 0; j < 4; ++j) bj[j] = bias[n0 + wc * 64 + j * 16 + lr];
    float* epi = (float*)smem + wv * (16 * 64);   // 4 KiB per wave (reuses staging LDS)
    const int latBase = (n0 >> 2) + wc * 16;
    for (int i = 0; i < 4; ++i) {                 // 16-row chunks
      __syncthreads();                            // protect prev chunk's reads
#pragma unroll
      for (int j = 0; j < 4; ++j)
#pragma unroll
        for (int ii = 0; ii < 4; ++ii)
          epi[(4 * lq + ii) * 64 + j * 16 + lr] = acc[i][j][ii] + bj[j];
      __syncthreads();
#pragma unroll
      for (int rb = 0; rb < 4; ++rb) {
        int rr = lq + 4 * rb;                     // 0..15
        int a  = lr;                              // latent within tile, 0..15
        f32x4 g = *(const f32x4*)(epi + rr * 64 + a * 4);  // [r̂, ẑ, i_n, h_n]
        int token = m0 + wr * 64 + i * 16 + rr;
        int latc  = latBase + a;
        float h  = hIn[(size_t)token * LAT + latc];
        float r  = sigmoidf_(g.x);
        float z  = sigmoidf_(g.y);
        float n  = tanhf_(g.z + r * g.w);
        float hn = (1.f - z) * n + z * h;
        outF[(size_t)token * LAT + latc] = hn;
        outB[(size_t)token * LAT + latc] = f32_to_bf16_rne(hn);
        traj[(size_t)token * (STEPS * LAT) + step * LAT + latc] = hn;
      }
    }
  }
}

// ---------------- launcher ----------------
extern "C" void kernel_launch(void* const* d_in, const int* in_sizes, int n_in,
                              void* d_out, int out_size, void* d_ws, size_t ws_size,
                              hipStream_t stream) {
  const float* hs  = (const float*)d_in[0];
  const float* We1 = (const float*)d_in[2];
  const float* be1 = (const float*)d_in[3];
  const float* We2 = (const float*)d_in[4];
  const float* be2 = (const float*)d_in[5];
  const float* Wd1 = (const float*)d_in[6];
  const float* bd1 = (const float*)d_in[7];
  const float* Wd2 = (const float*)d_in[8];
  const float* bd2 = (const float*)d_in[9];
  const float* wih = (const float*)d_in[10];
  const float* whh = (const float*)d_in[11];
  const float* bih = (const float*)d_in[12];
  const float* bhh = (const float*)d_in[13];

  char* ws = (char*)d_ws;
  unsigned short* A0    = (unsigned short*)(ws + 0);          // 33,554,432 B
  unsigned short* We1b  = (unsigned short*)(ws + 33554432);   //  4,194,304
  unsigned short* We2b  = (unsigned short*)(ws + 37748736);   //  1,048,576
  unsigned short* Wd1b  = (unsigned short*)(ws + 38797312);   //  1,048,576
  unsigned short* Wd2b  = (unsigned short*)(ws + 39845888);   //  4,194,304
  unsigned short* Wg    = (unsigned short*)(ws + 44040192);   //  2,097,152
  float*          biasg = (float*)         (ws + 46137344);   //      8,192
  unsigned short* X1    = (unsigned short*)(ws + 46145536);   // 16,777,216
  float*          Lf0   = (float*)         (ws + 62922752);   // 16,777,216
  float*          Lf1   = (float*)         (ws + 79699968);   // 16,777,216
  unsigned short* Lb0   = (unsigned short*)(ws + 96477184);   //  8,388,608
  unsigned short* Lb1   = (unsigned short*)(ws + 104865792);  //  8,388,608  -> total ~113 MB
  unsigned short* X2    = A0;                                 // A0 dead after E1

  float* dec  = (float*)d_out;
  float* traj = (float*)d_out + DEC_ELEMS;

  // prep: fp32 -> bf16 casts + GRU weight packing
  k_cast<<<2048, 256, 0, stream>>>(hs,  A0,   TOKENS * HID / 4);
  k_cast<<<512,  256, 0, stream>>>(We1, We1b, LAT2 * HID / 4);
  k_cast<<<256,  256, 0, stream>>>(We2, We2b, LAT * LAT2 / 4);
  k_cast<<<256,  256, 0, stream>>>(Wd1, Wd1b, LAT2 * LAT / 4);
  k_cast<<<512,  256, 0, stream>>>(Wd2, Wd2b, HID * LAT2 / 4);
  k_gru_pack<<<GCOLS, 128, 0, stream>>>(wih, whh, bih, bhh, Wg, biasg);

  dim3 blk(256);
  // encode
  gemm_bt<0><<<dim3(TOKENS / MWG, LAT2 / NWG), blk, 0, stream>>>(
      A0, We1b, be1, HID, LAT2, nullptr, X1, nullptr, nullptr, 0);
  gemm_bt<1><<<dim3(TOKENS / MWG, LAT / NWG), blk, 0, stream>>>(
      X1, We2b, be2, LAT2, LAT, Lf0, Lb0, nullptr, nullptr, 0);
  // GRU steps (double-buffered latent)
  for (int s = 0; s < STEPS; ++s) {
    const unsigned short* lbi = (s & 1) ? Lb1 : Lb0;
    const float*          lfi = (s & 1) ? Lf1 : Lf0;
    unsigned short*       lbo = (s & 1) ? Lb0 : Lb1;
    float*                lfo = (s & 1) ? Lf0 : Lf1;
    gemm_bt<3><<<dim3(TOKENS / MWG, GCOLS / NWG), blk, 0, stream>>>(
        lbi, Wg, biasg, LAT, GCOLS, lfo, lbo, lfi, traj, s);
  }
  // decode (after 8 steps latent is in buffer 0)
  gemm_bt<0><<<dim3(TOKENS / MWG, LAT2 / NWG), blk, 0, stream>>>(
      Lb0, Wd1b, bd1, LAT, LAT2, nullptr, X2, nullptr, nullptr, 0);
  gemm_bt<2><<<dim3(TOKENS / MWG, HID / NWG), blk, 0, stream>>>(
      X2, Wd2b, bd2, LAT2, HID, dec, nullptr, nullptr, nullptr, 0);
}

// Round 2
// 463.337 us; speedup vs baseline: 1.0722x; 1.0722x over previous
//
#include <hip/hip_runtime.h>
#include <hip/hip_bf16.h>
#include <cstdint>
#include <cstddef>

// ---------------- problem constants ----------------
#define TOKENS   8192          // B*S
#define HID      2048
#define LAT      512
#define LAT2     1024
#define GCOLS    2048          // 4 gates * LAT (packed col = 4*l + g)
#define STEPS    8
#define DEC_ELEMS (TOKENS*HID)

typedef __attribute__((ext_vector_type(8))) __bf16 bf16x8;
typedef __attribute__((ext_vector_type(4))) float  f32x4;

// ---------------- helpers ----------------
__device__ __forceinline__ unsigned short f32_to_bf16_rne(float f) {
  unsigned int u = __float_as_uint(f);
  unsigned int r = (u + 0x7FFFu + ((u >> 16) & 1u)) >> 16;
  return (unsigned short)r;
}

__device__ __forceinline__ float sigmoidf_(float x) {
  if (x >= 0.f) { float e = __expf(-x); return 1.f / (1.f + e); }
  float e = __expf(x); return e / (1.f + e);
}
__device__ __forceinline__ float tanhf_(float x) {
  float ax = fabsf(x);
  float e  = __expf(-2.f * ax);
  float t  = (1.f - e) / (1.f + e);
  return copysignf(t, x);
}

__device__ __forceinline__ void gl_lds16(const void* g, void* l) {
  __builtin_amdgcn_global_load_lds(
      (const __attribute__((address_space(1))) void*)g,
      (__attribute__((address_space(3))) void*)l, 16, 0, 0);
}

// ---------------- prep kernels ----------------
__global__ void k_cast(const float* __restrict__ s, unsigned short* __restrict__ d, int n4) {
  int i = blockIdx.x * blockDim.x + threadIdx.x;
  int stride = gridDim.x * blockDim.x;
  for (; i < n4; i += stride) {
    float4 v = ((const float4*)s)[i];
    ushort4 o;
    o.x = f32_to_bf16_rne(v.x);
    o.y = f32_to_bf16_rne(v.y);
    o.z = f32_to_bf16_rne(v.z);
    o.w = f32_to_bf16_rne(v.w);
    ((ushort4*)d)[i] = o;
  }
}

// Pack GRU weights: output row gc = 4*l + g, g in {0:r-sum, 1:z-sum, 2:i_n, 3:h_n}
__global__ void k_gru_pack(const float* __restrict__ wih, const float* __restrict__ whh,
                           const float* __restrict__ bih, const float* __restrict__ bhh,
                           unsigned short* __restrict__ Wg, float* __restrict__ biasg) {
  int gc = blockIdx.x;            // 0..2047
  int l  = gc >> 2;
  int g  = gc & 3;
  int row = (g == 0) ? l : (g == 1) ? (512 + l) : (1024 + l);
  for (int c = threadIdx.x; c < LAT; c += blockDim.x) {
    float v;
    if (g <= 1)      v = wih[row * LAT + c] + whh[row * LAT + c];
    else if (g == 2) v = wih[row * LAT + c];
    else             v = whh[row * LAT + c];
    Wg[(size_t)gc * LAT + c] = f32_to_bf16_rne(v);
  }
  if (threadIdx.x == 0) {
    float b;
    if (g <= 1)      b = bih[row] + bhh[row];
    else if (g == 2) b = bih[row];
    else             b = bhh[row];
    biasg[gc] = b;
  }
}

// =======================================================================
// 128x128 2-barrier kernel (kept for small-N GEMMs: E2, D1)
// =======================================================================
#define MWG 128
#define NWG 128
#define KTILE 64

template <int EPI>
__global__ __launch_bounds__(256)
void gemm_bt(const unsigned short* __restrict__ A,   // [M x K] bf16 bits
             const unsigned short* __restrict__ W,   // [N x K] bf16 bits
             const float* __restrict__ bias,         // [N]
             int K, int N,
             float* __restrict__ outF,
             unsigned short* __restrict__ outB,
             const float* __restrict__ hIn,
             float* __restrict__ traj,
             int step) {
  __shared__ __align__(16) char smem[2 * MWG * KTILE * 2];   // 32 KiB
  unsigned short* As = (unsigned short*)smem;
  unsigned short* Bs = As + MWG * KTILE;

  const int tid  = threadIdx.x;
  const int lane = tid & 63;
  const int wv   = tid >> 6;        // 4 waves
  const int wr   = wv >> 1;         // 0/1
  const int wc   = wv & 1;          // 0/1
  const int m0   = blockIdx.x * MWG;
  const int n0   = blockIdx.y * NWG;

  const int lr = lane & 15;         // fragment row (A) / col (B/D)
  const int lq = lane >> 4;         // k-group 0..3

  const int srow = lane >> 3;       // staging: row within 8-row chunk
  const int scol = (lane & 7) * 8;  // staging: element col

  f32x4 acc[4][4];
#pragma unroll
  for (int i = 0; i < 4; ++i)
#pragma unroll
    for (int j = 0; j < 4; ++j) acc[i][j] = (f32x4){0.f, 0.f, 0.f, 0.f};

  const unsigned short* Ab = A + (size_t)m0 * K;
  const unsigned short* Wb = W + (size_t)n0 * K;

  const int KT = K / KTILE;
  for (int kt = 0; kt < KT; ++kt) {
    const int k0 = kt * KTILE;
#pragma unroll
    for (int q = 0; q < 4; ++q) {
      int row = 32 * wv + 8 * q + srow;
      gl_lds16(Ab + (size_t)row * K + k0 + scol, As + (32 * wv + 8 * q) * KTILE);
      gl_lds16(Wb + (size_t)row * K + k0 + scol, Bs + (32 * wv + 8 * q) * KTILE);
    }
    __syncthreads();
#pragma unroll
    for (int kk = 0; kk < KTILE; kk += 32) {
      bf16x8 af[4], bf[4];
#pragma unroll
      for (int i = 0; i < 4; ++i)
        af[i] = *(const bf16x8*)(As + (wr * 64 + i * 16 + lr) * KTILE + kk + lq * 8);
#pragma unroll
      for (int j = 0; j < 4; ++j)
        bf[j] = *(const bf16x8*)(Bs + (wc * 64 + j * 16 + lr) * KTILE + kk + lq * 8);
#pragma unroll
      for (int i = 0; i < 4; ++i)
#pragma unroll
        for (int j = 0; j < 4; ++j)
          acc[i][j] = __builtin_amdgcn_mfma_f32_16x16x32_bf16(af[i], bf[j], acc[i][j], 0, 0, 0);
    }
    __syncthreads();
  }

  float bj[4];
#pragma unroll
  for (int j = 0; j < 4; ++j) bj[j] = bias[n0 + wc * 64 + j * 16 + lr];
#pragma unroll
  for (int i = 0; i < 4; ++i) {
#pragma unroll
    for (int ii = 0; ii < 4; ++ii) {
      int row = m0 + wr * 64 + i * 16 + 4 * lq + ii;
#pragma unroll
      for (int j = 0; j < 4; ++j) {
        int col = n0 + wc * 64 + j * 16 + lr;
        float v = acc[i][j][ii] + bj[j];
        if constexpr (EPI == 0) {
          v = fmaxf(v, 0.f);
          outB[(size_t)row * N + col] = f32_to_bf16_rne(v);
        } else if constexpr (EPI == 1) {
          outF[(size_t)row * N + col] = v;
          outB[(size_t)row * N + col] = f32_to_bf16_rne(v);
        } else {
          outF[(size_t)row * N + col] = v;
        }
      }
    }
  }
}

// =======================================================================
// 256x256 8-phase pipelined kernel (T2 swizzle + T3/T4 counted vmcnt + T5)
// 512 threads = 8 waves (2M x 4N); per-wave output 128x64; BK=64.
// LDS 128 KiB: buf{0,1} x {A[256][64], B[256][64]} bf16.
// =======================================================================

#define WAIT_LGKM0() asm volatile("s_waitcnt lgkmcnt(0)" ::: "memory")
#define WAIT_VM(n)   asm volatile("s_waitcnt vmcnt(" #n ")" ::: "memory")

#define LOAD_A(buf, mh) { \
  const int baseA = (buf)*65536 + wm*16384; \
  _Pragma("unroll") for (int m4 = 0; m4 < 4; ++m4) \
  _Pragma("unroll") for (int kki = 0; kki < 2; ++kki) { \
    int rl = (mh)*64 + m4*16 + lr; \
    int off = (rl*128 + kki*64 + lq*16) ^ ((rl & 7) << 4); \
    aR[mh][m4][kki] = *(const bf16x8*)(lds_ + baseA + off); } }

#define LOAD_B(buf, nh) { \
  const int baseB = (buf)*65536 + 32768 + (wn >> 1)*16384; \
  _Pragma("unroll") for (int n2 = 0; n2 < 2; ++n2) \
  _Pragma("unroll") for (int kki = 0; kki < 2; ++kki) { \
    int rl = (wn & 1)*64 + ((nh)*2 + n2)*16 + lr; \
    int off = (rl*128 + kki*64 + lq*16) ^ ((rl & 7) << 4); \
    bR[nh][n2][kki] = *(const bf16x8*)(lds_ + baseB + off); } }

#define STAGE_A(buf, half, kt) { \
  const unsigned short* gp = A + (size_t)(m0 + (half)*128 + rr8)*K + (size_t)(kt)*64 + cc8; \
  char* dp = lds_ + (buf)*65536 + (half)*16384 + (wv << 10); \
  gl_lds16(gp, dp); \
  gl_lds16(gp + (size_t)64*K, dp + 8192); }

#define STAGE_B(buf, half, kt) { \
  const unsigned short* gp = W + (size_t)(n0 + (half)*128 + rr8)*K + (size_t)(kt)*64 + cc8; \
  char* dp = lds_ + (buf)*65536 + 32768 + (half)*16384 + (wv << 10); \
  gl_lds16(gp, dp); \
  gl_lds16(gp + (size_t)64*K, dp + 8192); }

#define MFMAQ(mh, nh) \
  _Pragma("unroll") for (int kki = 0; kki < 2; ++kki) \
  _Pragma("unroll") for (int n2 = 0; n2 < 2; ++n2) \
  _Pragma("unroll") for (int m4 = 0; m4 < 4; ++m4) \
    acc[(mh)*4 + m4][(nh)*2 + n2] = __builtin_amdgcn_mfma_f32_16x16x32_bf16( \
        aR[mh][m4][kki], bR[nh][n2][kki], acc[(mh)*4 + m4][(nh)*2 + n2], 0, 0, 0);

#define PH_CORE(mh, nh) \
  __builtin_amdgcn_s_barrier(); \
  WAIT_LGKM0(); \
  __builtin_amdgcn_sched_barrier(0); \
  __builtin_amdgcn_s_setprio(1); \
  MFMAQ(mh, nh); \
  __builtin_amdgcn_sched_barrier(0); \
  __builtin_amdgcn_s_setprio(0);

#define PH_BAR() __builtin_amdgcn_s_barrier();

template <int EPI>
__global__ __launch_bounds__(512, 2)
void gemm256(const unsigned short* __restrict__ A,   // [M x K] bf16 bits
             const unsigned short* __restrict__ W,   // [N x K] bf16 bits
             const float* __restrict__ bias,         // [N]
             int K, int N, int Ntiles,
             float* __restrict__ outF,
             unsigned short* __restrict__ outB,
             const float* __restrict__ hIn,
             float* __restrict__ traj,
             int step) {
  __shared__ __align__(16) char lds_[131072];   // 128 KiB

  const int tid  = threadIdx.x;
  const int lane = tid & 63;
  const int wv   = tid >> 6;        // 8 waves
  const int wm   = wv >> 2;         // 0/1 : M half (128 rows)
  const int wn   = wv & 3;          // 0..3 : N quarter (64 cols)
  const int lr   = lane & 15;
  const int lq   = lane >> 4;

  // staging lane constants (inverse-swizzled global source, linear LDS dest)
  const int rr8 = (wv << 3) + (lane >> 3);            // row 0..63 (+64 for 2nd)
  const int cc8 = ((lane & 7) ^ (lane >> 3)) << 3;    // element col (pre-swizzled)

  // XCD-aware swizzle (bijective: gridDim.x % 8 == 0)
  {
  }
  const int nwg = gridDim.x;
  const int wg  = blockIdx.x;
  const int swz = (wg & 7) * (nwg >> 3) + (wg >> 3);
  const int tm  = swz / Ntiles;
  const int tn  = swz % Ntiles;
  const int m0  = tm * 256;
  const int n0  = tn * 256;

  f32x4 acc[8][4];
#pragma unroll
  for (int i = 0; i < 8; ++i)
#pragma unroll
    for (int j = 0; j < 4; ++j) acc[i][j] = (f32x4){0.f, 0.f, 0.f, 0.f};

  bf16x8 aR[2][4][2];
  bf16x8 bR[2][2][2];

  const int nIt = K >> 7;           // iterations; each covers 2 K-tiles of 64

  // ---- prologue: stage kt0 {B0,B1,A0,A1}, kt1 {B0,B1} ----
  STAGE_B(0, 0, 0) STAGE_B(0, 1, 0) STAGE_A(0, 0, 0) STAGE_A(0, 1, 0)
  STAGE_B(1, 0, 1) STAGE_B(1, 1, 1)
  WAIT_VM(4);
  __builtin_amdgcn_s_barrier();

  for (int t = 0; t < nIt - 1; ++t) {
    const int kt1 = 2 * t + 1;
    const int kt2 = 2 * t + 2;
    const int kt3 = 2 * t + 3;
    // ph1
    LOAD_A(0, 0) LOAD_B(0, 0)
    STAGE_A(1, 0, kt1)
    PH_CORE(0, 0) PH_BAR()
    // ph2
    LOAD_B(0, 1)
    STAGE_A(1, 1, kt1)
    PH_CORE(0, 1) PH_BAR()
    // ph3
    LOAD_A(0, 1)
    STAGE_B(0, 0, kt2)
    PH_CORE(1, 1) PH_BAR()
    // ph4
    STAGE_B(0, 1, kt2)
    PH_CORE(1, 0)
    WAIT_VM(4);
    PH_BAR()
    // ph5
    LOAD_A(1, 0) LOAD_B(1, 0)
    STAGE_A(0, 0, kt2)
    PH_CORE(0, 0) PH_BAR()
    // ph6
    LOAD_B(1, 1)
    STAGE_A(0, 1, kt2)
    PH_CORE(0, 1) PH_BAR()
    // ph7
    LOAD_A(1, 1)
    STAGE_B(1, 0, kt3)
    PH_CORE(1, 1) PH_BAR()
    // ph8
    STAGE_B(1, 1, kt3)
    PH_CORE(1, 0)
    WAIT_VM(4);
    PH_BAR()
  }

  // ---- last iteration (kt0 = K/64-2, kt1 = K/64-1): only A-stages of kt1 ----
  {
    const int ktL = 2 * nIt - 1;
    LOAD_A(0, 0) LOAD_B(0, 0)
    STAGE_A(1, 0, ktL)
    PH_CORE(0, 0) PH_BAR()
    LOAD_B(0, 1)
    STAGE_A(1, 1, ktL)
    PH_CORE(0, 1) PH_BAR()
    LOAD_A(0, 1)
    PH_CORE(1, 1) PH_BAR()
    PH_CORE(1, 0)
    WAIT_VM(0);
    PH_BAR()
    LOAD_A(1, 0) LOAD_B(1, 0)
    PH_CORE(0, 0) PH_BAR()
    LOAD_B(1, 1)
    PH_CORE(0, 1) PH_BAR()
    LOAD_A(1, 1)
    PH_CORE(1, 1) PH_BAR()
    PH_CORE(1, 0)
    PH_BAR()
  }

  // ---------------- epilogues ----------------
  float bj[4];
#pragma unroll
  for (int nf = 0; nf < 4; ++nf) bj[nf] = bias[n0 + wn * 64 + nf * 16 + lr];

  if constexpr (EPI == 0 || EPI == 1 || EPI == 2) {
#pragma unroll
    for (int mf = 0; mf < 8; ++mf) {
#pragma unroll
      for (int ii = 0; ii < 4; ++ii) {
        int row = m0 + wm * 128 + mf * 16 + lq * 4 + ii;
#pragma unroll
        for (int nf = 0; nf < 4; ++nf) {
          int col = n0 + wn * 64 + nf * 16 + lr;
          float v = acc[mf][nf][ii] + bj[nf];
          if constexpr (EPI == 0) {
            v = fmaxf(v, 0.f);
            outB[(size_t)row * N + col] = f32_to_bf16_rne(v);
          } else if constexpr (EPI == 1) {
            outF[(size_t)row * N + col] = v;
            outB[(size_t)row * N + col] = f32_to_bf16_rne(v);
          } else {
            outF[(size_t)row * N + col] = v;
          }
        }
      }
    }
  } else {
    // GRU gate epilogue: wave tile = 128 tokens x 64 gate cols = 16 latents
    float* scr = (float*)lds_ + wv * 1088;      // 16 x 68 floats per wave
    const int latBase = tn * 64 + wn * 16;
    const int la = lane & 15;
    const int th = lane >> 4;
#pragma unroll
    for (int mf = 0; mf < 8; ++mf) {
      WAIT_LGKM0();
#pragma unroll
      for (int nf = 0; nf < 4; ++nf)
#pragma unroll
        for (int ii = 0; ii < 4; ++ii)
          scr[(lq * 4 + ii) * 68 + nf * 16 + lr] = acc[mf][nf][ii] + bj[nf];
      WAIT_LGKM0();
#pragma unroll
      for (int tb = 0; tb < 4; ++tb) {
        int tt = th * 4 + tb;
        int token = m0 + wm * 128 + mf * 16 + tt;
        f32x4 g = *(const f32x4*)(scr + tt * 68 + la * 4);  // [r̂, ẑ, i_n, h_n]
        int latc = latBase + la;
        float h  = hIn[(size_t)token * LAT + latc];
        float r  = sigmoidf_(g.x);
        float z  = sigmoidf_(g.y);
        float n  = tanhf_(g.z + r * g.w);
        float hn = (1.f - z) * n + z * h;
        outF[(size_t)token * LAT + latc] = hn;
        outB[(size_t)token * LAT + latc] = f32_to_bf16_rne(hn);
        traj[(size_t)token * (STEPS * LAT) + step * LAT + latc] = hn;
      }
    }
  }
}

// ---------------- launcher ----------------
extern "C" void kernel_launch(void* const* d_in, const int* in_sizes, int n_in,
                              void* d_out, int out_size, void* d_ws, size_t ws_size,
                              hipStream_t stream) {
  const float* hs  = (const float*)d_in[0];
  const float* We1 = (const float*)d_in[2];
  const float* be1 = (const float*)d_in[3];
  const float* We2 = (const float*)d_in[4];
  const float* be2 = (const float*)d_in[5];
  const float* Wd1 = (const float*)d_in[6];
  const float* bd1 = (const float*)d_in[7];
  const float* Wd2 = (const float*)d_in[8];
  const float* bd2 = (const float*)d_in[9];
  const float* wih = (const float*)d_in[10];
  const float* whh = (const float*)d_in[11];
  const float* bih = (const float*)d_in[12];
  const float* bhh = (const float*)d_in[13];

  char* ws = (char*)d_ws;
  unsigned short* A0    = (unsigned short*)(ws + 0);          // 33,554,432 B
  unsigned short* We1b  = (unsigned short*)(ws + 33554432);   //  4,194,304
  unsigned short* We2b  = (unsigned short*)(ws + 37748736);   //  1,048,576
  unsigned short* Wd1b  = (unsigned short*)(ws + 38797312);   //  1,048,576
  unsigned short* Wd2b  = (unsigned short*)(ws + 39845888);   //  4,194,304
  unsigned short* Wg    = (unsigned short*)(ws + 44040192);   //  2,097,152
  float*          biasg = (float*)         (ws + 46137344);   //      8,192
  unsigned short* X1    = (unsigned short*)(ws + 46145536);   // 16,777,216
  float*          Lf0   = (float*)         (ws + 62922752);   // 16,777,216
  float*          Lf1   = (float*)         (ws + 79699968);   // 16,777,216
  unsigned short* Lb0   = (unsigned short*)(ws + 96477184);   //  8,388,608
  unsigned short* Lb1   = (unsigned short*)(ws + 104865792);  //  8,388,608
  unsigned short* X2    = A0;                                 // A0 dead after E1

  float* dec  = (float*)d_out;
  float* traj = (float*)d_out + DEC_ELEMS;

  // prep: fp32 -> bf16 casts + GRU weight packing
  k_cast<<<2048, 256, 0, stream>>>(hs,  A0,   TOKENS * HID / 4);
  k_cast<<<512,  256, 0, stream>>>(We1, We1b, LAT2 * HID / 4);
  k_cast<<<256,  256, 0, stream>>>(We2, We2b, LAT * LAT2 / 4);
  k_cast<<<256,  256, 0, stream>>>(Wd1, Wd1b, LAT2 * LAT / 4);
  k_cast<<<512,  256, 0, stream>>>(Wd2, Wd2b, HID * LAT2 / 4);
  k_gru_pack<<<GCOLS, 128, 0, stream>>>(wih, whh, bih, bhh, Wg, biasg);

  // encode
  gemm256<0><<<128, 512, 0, stream>>>(A0, We1b, be1, HID, LAT2, 4,
                                      nullptr, X1, nullptr, nullptr, 0);
  gemm_bt<1><<<dim3(TOKENS / MWG, LAT / NWG), dim3(256), 0, stream>>>(
      X1, We2b, be2, LAT2, LAT, Lf0, Lb0, nullptr, nullptr, 0);
  // GRU steps (double-buffered latent), 256^2 8-phase fused-gate kernel
  for (int s = 0; s < STEPS; ++s) {
    const unsigned short* lbi = (s & 1) ? Lb1 : Lb0;
    const float*          lfi = (s & 1) ? Lf1 : Lf0;
    unsigned short*       lbo = (s & 1) ? Lb0 : Lb1;
    float*                lfo = (s & 1) ? Lf0 : Lf1;
    gemm256<3><<<256, 512, 0, stream>>>(lbi, Wg, biasg, LAT, GCOLS, 8,
                                        lfo, lbo, lfi, traj, s);
  }
  // decode (after 8 steps latent is in buffer 0)
  gemm_bt<0><<<dim3(TOKENS / MWG, LAT2 / NWG), dim3(256), 0, stream>>>(
      Lb0, Wd1b, bd1, LAT, LAT2, nullptr, X2, nullptr, nullptr, 0);
  gemm256<2><<<256, 512, 0, stream>>>(X2, Wd2b, bd2, LAT2, HID, 8,
                                      dec, nullptr, nullptr, nullptr, 0);
}

// Round 3
// 439.951 us; speedup vs baseline: 1.1292x; 1.0532x over previous
//
#include <hip/hip_runtime.h>
#include <hip/hip_bf16.h>
#include <cstdint>
#include <cstddef>

// ---------------- problem constants ----------------
#define TOKENS   8192          // B*S
#define HID      2048
#define LAT      512
#define LAT2     1024
#define GCOLS    2048          // 4 gates * LAT (packed col = 4*l + g)
#define STEPS    8
#define DEC_ELEMS (TOKENS*HID)

typedef __attribute__((ext_vector_type(8))) __bf16 bf16x8;
typedef __attribute__((ext_vector_type(4))) float  f32x4;

// ---------------- helpers ----------------
__device__ __forceinline__ unsigned short f32_to_bf16_rne(float f) {
  unsigned int u = __float_as_uint(f);
  unsigned int r = (u + 0x7FFFu + ((u >> 16) & 1u)) >> 16;
  return (unsigned short)r;
}
__device__ __forceinline__ float bf16_to_f32(unsigned short u) {
  return __uint_as_float(((unsigned int)u) << 16);
}

__device__ __forceinline__ float sigmoidf_(float x) {
  if (x >= 0.f) { float e = __expf(-x); return 1.f / (1.f + e); }
  float e = __expf(x); return e / (1.f + e);
}
__device__ __forceinline__ float tanhf_(float x) {
  float ax = fabsf(x);
  float e  = __expf(-2.f * ax);
  float t  = (1.f - e) / (1.f + e);
  return copysignf(t, x);
}

__device__ __forceinline__ void gl_lds16(const void* g, void* l) {
  __builtin_amdgcn_global_load_lds(
      (const __attribute__((address_space(1))) void*)g,
      (__attribute__((address_space(3))) void*)l, 16, 0, 0);
}

// ---------------- prep kernels ----------------
__global__ void k_cast(const float* __restrict__ s, unsigned short* __restrict__ d, int n4) {
  int i = blockIdx.x * blockDim.x + threadIdx.x;
  int stride = gridDim.x * blockDim.x;
  for (; i < n4; i += stride) {
    float4 v = ((const float4*)s)[i];
    ushort4 o;
    o.x = f32_to_bf16_rne(v.x);
    o.y = f32_to_bf16_rne(v.y);
    o.z = f32_to_bf16_rne(v.z);
    o.w = f32_to_bf16_rne(v.w);
    ((ushort4*)d)[i] = o;
  }
}

// Pack GRU weights: output row gc = 4*l + g, g in {0:r-sum, 1:z-sum, 2:i_n, 3:h_n}
__global__ void k_gru_pack(const float* __restrict__ wih, const float* __restrict__ whh,
                           const float* __restrict__ bih, const float* __restrict__ bhh,
                           unsigned short* __restrict__ Wg, float* __restrict__ biasg) {
  int gc = blockIdx.x;            // 0..2047
  int l  = gc >> 2;
  int g  = gc & 3;
  int row = (g == 0) ? l : (g == 1) ? (512 + l) : (1024 + l);
  for (int c = threadIdx.x; c < LAT; c += blockDim.x) {
    float v;
    if (g <= 1)      v = wih[row * LAT + c] + whh[row * LAT + c];
    else if (g == 2) v = wih[row * LAT + c];
    else             v = whh[row * LAT + c];
    Wg[(size_t)gc * LAT + c] = f32_to_bf16_rne(v);
  }
  if (threadIdx.x == 0) {
    float b;
    if (g <= 1)      b = bih[row] + bhh[row];
    else if (g == 2) b = bih[row];
    else             b = bhh[row];
    biasg[gc] = b;
  }
}

// =======================================================================
// 128x128 2-barrier kernel (E1, E2, D1)
// EPI 0: outB = bf16(relu(acc+bias))
// EPI 1: outB = bf16(acc+bias)
// EPI 2: outF = acc+bias
// =======================================================================
#define MWG 128
#define NWG 128
#define KTILE 64

template <int EPI>
__global__ __launch_bounds__(256)
void gemm_bt(const unsigned short* __restrict__ A,   // [M x K] bf16 bits
             const unsigned short* __restrict__ W,   // [N x K] bf16 bits
             const float* __restrict__ bias,         // [N]
             int K, int N,
             float* __restrict__ outF,
             unsigned short* __restrict__ outB) {
  __shared__ __align__(16) char smem[2 * MWG * KTILE * 2];   // 32 KiB
  unsigned short* As = (unsigned short*)smem;
  unsigned short* Bs = As + MWG * KTILE;

  const int tid  = threadIdx.x;
  const int lane = tid & 63;
  const int wv   = tid >> 6;        // 4 waves
  const int wr   = wv >> 1;         // 0/1
  const int wc   = wv & 1;          // 0/1
  const int m0   = blockIdx.x * MWG;
  const int n0   = blockIdx.y * NWG;

  const int lr = lane & 15;         // fragment row (A) / col (B/D)
  const int lq = lane >> 4;         // k-group 0..3

  const int srow = lane >> 3;       // staging: row within 8-row chunk
  const int scol = (lane & 7) * 8;  // staging: element col

  f32x4 acc[4][4];
#pragma unroll
  for (int i = 0; i < 4; ++i)
#pragma unroll
    for (int j = 0; j < 4; ++j) acc[i][j] = (f32x4){0.f, 0.f, 0.f, 0.f};

  const unsigned short* Ab = A + (size_t)m0 * K;
  const unsigned short* Wb = W + (size_t)n0 * K;

  const int KT = K / KTILE;
  for (int kt = 0; kt < KT; ++kt) {
    const int k0 = kt * KTILE;
#pragma unroll
    for (int q = 0; q < 4; ++q) {
      int row = 32 * wv + 8 * q + srow;
      gl_lds16(Ab + (size_t)row * K + k0 + scol, As + (32 * wv + 8 * q) * KTILE);
      gl_lds16(Wb + (size_t)row * K + k0 + scol, Bs + (32 * wv + 8 * q) * KTILE);
    }
    __syncthreads();
#pragma unroll
    for (int kk = 0; kk < KTILE; kk += 32) {
      bf16x8 af[4], bf[4];
#pragma unroll
      for (int i = 0; i < 4; ++i)
        af[i] = *(const bf16x8*)(As + (wr * 64 + i * 16 + lr) * KTILE + kk + lq * 8);
#pragma unroll
      for (int j = 0; j < 4; ++j)
        bf[j] = *(const bf16x8*)(Bs + (wc * 64 + j * 16 + lr) * KTILE + kk + lq * 8);
#pragma unroll
      for (int i = 0; i < 4; ++i)
#pragma unroll
        for (int j = 0; j < 4; ++j)
          acc[i][j] = __builtin_amdgcn_mfma_f32_16x16x32_bf16(af[i], bf[j], acc[i][j], 0, 0, 0);
    }
    __syncthreads();
  }

  float bj[4];
#pragma unroll
  for (int j = 0; j < 4; ++j) bj[j] = bias[n0 + wc * 64 + j * 16 + lr];
#pragma unroll
  for (int i = 0; i < 4; ++i) {
#pragma unroll
    for (int ii = 0; ii < 4; ++ii) {
      int row = m0 + wr * 64 + i * 16 + 4 * lq + ii;
#pragma unroll
      for (int j = 0; j < 4; ++j) {
        int col = n0 + wc * 64 + j * 16 + lr;
        float v = acc[i][j][ii] + bj[j];
        if constexpr (EPI == 0) {
          outB[(size_t)row * N + col] = f32_to_bf16_rne(fmaxf(v, 0.f));
        } else if constexpr (EPI == 1) {
          outB[(size_t)row * N + col] = f32_to_bf16_rne(v);
        } else {
          outF[(size_t)row * N + col] = v;
        }
      }
    }
  }
}

// =======================================================================
// 256x256 8-phase pipelined kernel (T2 swizzle + T3/T4 counted vmcnt + T5)
// 512 threads = 8 waves (2M x 4N); per-wave output 128x64; BK=64.
// LDS 128 KiB: buf{0,1} x {A[256][64], B[256][64]} bf16.
// EPI 2: outF = acc+bias (D2)
// EPI 3: GRU gate epilogue, h carried in bf16 (hInB), writes outB + traj
// =======================================================================

#define WAIT_LGKM0() asm volatile("s_waitcnt lgkmcnt(0)" ::: "memory")
#define WAIT_VM(n)   asm volatile("s_waitcnt vmcnt(" #n ")" ::: "memory")

#define LOAD_A(buf, mh) { \
  const int baseA = (buf)*65536 + wm*16384; \
  _Pragma("unroll") for (int m4 = 0; m4 < 4; ++m4) \
  _Pragma("unroll") for (int kki = 0; kki < 2; ++kki) { \
    int rl = (mh)*64 + m4*16 + lr; \
    int off = (rl*128 + kki*64 + lq*16) ^ ((rl & 7) << 4); \
    aR[mh][m4][kki] = *(const bf16x8*)(lds_ + baseA + off); } }

#define LOAD_B(buf, nh) { \
  const int baseB = (buf)*65536 + 32768 + (wn >> 1)*16384; \
  _Pragma("unroll") for (int n2 = 0; n2 < 2; ++n2) \
  _Pragma("unroll") for (int kki = 0; kki < 2; ++kki) { \
    int rl = (wn & 1)*64 + ((nh)*2 + n2)*16 + lr; \
    int off = (rl*128 + kki*64 + lq*16) ^ ((rl & 7) << 4); \
    bR[nh][n2][kki] = *(const bf16x8*)(lds_ + baseB + off); } }

#define STAGE_A(buf, half, kt) { \
  const unsigned short* gp = A + (size_t)(m0 + (half)*128 + rr8)*K + (size_t)(kt)*64 + cc8; \
  char* dp = lds_ + (buf)*65536 + (half)*16384 + (wv << 10); \
  gl_lds16(gp, dp); \
  gl_lds16(gp + (size_t)64*K, dp + 8192); }

#define STAGE_B(buf, half, kt) { \
  const unsigned short* gp = W + (size_t)(n0 + (half)*128 + rr8)*K + (size_t)(kt)*64 + cc8; \
  char* dp = lds_ + (buf)*65536 + 32768 + (half)*16384 + (wv << 10); \
  gl_lds16(gp, dp); \
  gl_lds16(gp + (size_t)64*K, dp + 8192); }

#define MFMAQ(mh, nh) \
  _Pragma("unroll") for (int kki = 0; kki < 2; ++kki) \
  _Pragma("unroll") for (int n2 = 0; n2 < 2; ++n2) \
  _Pragma("unroll") for (int m4 = 0; m4 < 4; ++m4) \
    acc[(mh)*4 + m4][(nh)*2 + n2] = __builtin_amdgcn_mfma_f32_16x16x32_bf16( \
        aR[mh][m4][kki], bR[nh][n2][kki], acc[(mh)*4 + m4][(nh)*2 + n2], 0, 0, 0);

#define PH_CORE(mh, nh) \
  __builtin_amdgcn_s_barrier(); \
  WAIT_LGKM0(); \
  __builtin_amdgcn_sched_barrier(0); \
  __builtin_amdgcn_s_setprio(1); \
  MFMAQ(mh, nh); \
  __builtin_amdgcn_sched_barrier(0); \
  __builtin_amdgcn_s_setprio(0);

#define PH_BAR() __builtin_amdgcn_s_barrier();

template <int EPI>
__global__ __launch_bounds__(512, 2)
void gemm256(const unsigned short* __restrict__ A,   // [M x K] bf16 bits
             const unsigned short* __restrict__ W,   // [N x K] bf16 bits
             const float* __restrict__ bias,         // [N]
             int K, int N, int Ntiles,
             float* __restrict__ outF,
             unsigned short* __restrict__ outB,
             const unsigned short* __restrict__ hInB,
             float* __restrict__ traj,
             int step) {
  __shared__ __align__(16) char lds_[131072];   // 128 KiB

  const int tid  = threadIdx.x;
  const int lane = tid & 63;
  const int wv   = tid >> 6;        // 8 waves
  const int wm   = wv >> 2;         // 0/1 : M half (128 rows)
  const int wn   = wv & 3;          // 0..3 : N quarter (64 cols)
  const int lr   = lane & 15;
  const int lq   = lane >> 4;

  // staging lane constants (inverse-swizzled global source, linear LDS dest)
  const int rr8 = (wv << 3) + (lane >> 3);            // row 0..63 (+64 for 2nd)
  const int cc8 = ((lane & 7) ^ (lane >> 3)) << 3;    // element col (pre-swizzled)

  // XCD-aware swizzle (bijective: gridDim.x % 8 == 0)
  const int nwg = gridDim.x;
  const int wg  = blockIdx.x;
  const int swz = (wg & 7) * (nwg >> 3) + (wg >> 3);
  const int tm  = swz / Ntiles;
  const int tn  = swz % Ntiles;
  const int m0  = tm * 256;
  const int n0  = tn * 256;

  f32x4 acc[8][4];
#pragma unroll
  for (int i = 0; i < 8; ++i)
#pragma unroll
    for (int j = 0; j < 4; ++j) acc[i][j] = (f32x4){0.f, 0.f, 0.f, 0.f};

  bf16x8 aR[2][4][2];
  bf16x8 bR[2][2][2];

  const int nIt = K >> 7;           // iterations; each covers 2 K-tiles of 64

  // ---- prologue: stage kt0 {B0,B1,A0,A1}, kt1 {B0,B1} ----
  STAGE_B(0, 0, 0) STAGE_B(0, 1, 0) STAGE_A(0, 0, 0) STAGE_A(0, 1, 0)
  STAGE_B(1, 0, 1) STAGE_B(1, 1, 1)
  WAIT_VM(4);
  __builtin_amdgcn_s_barrier();

  for (int t = 0; t < nIt - 1; ++t) {
    const int kt1 = 2 * t + 1;
    const int kt2 = 2 * t + 2;
    const int kt3 = 2 * t + 3;
    // ph1
    LOAD_A(0, 0) LOAD_B(0, 0)
    STAGE_A(1, 0, kt1)
    PH_CORE(0, 0) PH_BAR()
    // ph2
    LOAD_B(0, 1)
    STAGE_A(1, 1, kt1)
    PH_CORE(0, 1) PH_BAR()
    // ph3
    LOAD_A(0, 1)
    STAGE_B(0, 0, kt2)
    PH_CORE(1, 1) PH_BAR()
    // ph4
    STAGE_B(0, 1, kt2)
    PH_CORE(1, 0)
    WAIT_VM(4);
    PH_BAR()
    // ph5
    LOAD_A(1, 0) LOAD_B(1, 0)
    STAGE_A(0, 0, kt2)
    PH_CORE(0, 0) PH_BAR()
    // ph6
    LOAD_B(1, 1)
    STAGE_A(0, 1, kt2)
    PH_CORE(0, 1) PH_BAR()
    // ph7
    LOAD_A(1, 1)
    STAGE_B(1, 0, kt3)
    PH_CORE(1, 1) PH_BAR()
    // ph8
    STAGE_B(1, 1, kt3)
    PH_CORE(1, 0)
    WAIT_VM(4);
    PH_BAR()
  }

  // ---- last iteration: only A-stages of last K-tile ----
  {
    const int ktL = 2 * nIt - 1;
    LOAD_A(0, 0) LOAD_B(0, 0)
    STAGE_A(1, 0, ktL)
    PH_CORE(0, 0) PH_BAR()
    LOAD_B(0, 1)
    STAGE_A(1, 1, ktL)
    PH_CORE(0, 1) PH_BAR()
    LOAD_A(0, 1)
    PH_CORE(1, 1) PH_BAR()
    PH_CORE(1, 0)
    WAIT_VM(0);
    PH_BAR()
    LOAD_A(1, 0) LOAD_B(1, 0)
    PH_CORE(0, 0) PH_BAR()
    LOAD_B(1, 1)
    PH_CORE(0, 1) PH_BAR()
    LOAD_A(1, 1)
    PH_CORE(1, 1) PH_BAR()
    PH_CORE(1, 0)
    PH_BAR()
  }

  // ---------------- epilogues ----------------
  float bj[4];
#pragma unroll
  for (int nf = 0; nf < 4; ++nf) bj[nf] = bias[n0 + wn * 64 + nf * 16 + lr];

  if constexpr (EPI == 2) {
#pragma unroll
    for (int mf = 0; mf < 8; ++mf) {
#pragma unroll
      for (int ii = 0; ii < 4; ++ii) {
        int row = m0 + wm * 128 + mf * 16 + lq * 4 + ii;
#pragma unroll
        for (int nf = 0; nf < 4; ++nf) {
          int col = n0 + wn * 64 + nf * 16 + lr;
          outF[(size_t)row * N + col] = acc[mf][nf][ii] + bj[nf];
        }
      }
    }
  } else {
    // GRU gate epilogue: wave tile = 128 tokens x 64 gate cols = 16 latents
    // h carried in bf16: hInB == the GEMM A operand (L2-hot rows)
    float* scr = (float*)lds_ + wv * 1088;      // 16 x 68 floats per wave
    const int latBase = tn * 64 + wn * 16;
    const int la = lane & 15;
    const int th = lane >> 4;
#pragma unroll
    for (int mf = 0; mf < 8; ++mf) {
      WAIT_LGKM0();
#pragma unroll
      for (int nf = 0; nf < 4; ++nf)
#pragma unroll
        for (int ii = 0; ii < 4; ++ii)
          scr[(lq * 4 + ii) * 68 + nf * 16 + lr] = acc[mf][nf][ii] + bj[nf];
      WAIT_LGKM0();
#pragma unroll
      for (int tb = 0; tb < 4; ++tb) {
        int tt = th * 4 + tb;
        int token = m0 + wm * 128 + mf * 16 + tt;
        f32x4 g = *(const f32x4*)(scr + tt * 68 + la * 4);  // [r̂, ẑ, i_n, h_n]
        int latc = latBase + la;
        float h  = bf16_to_f32(hInB[(size_t)token * LAT + latc]);
        float r  = sigmoidf_(g.x);
        float z  = sigmoidf_(g.y);
        float n  = tanhf_(g.z + r * g.w);
        float hn = (1.f - z) * n + z * h;
        outB[(size_t)token * LAT + latc] = f32_to_bf16_rne(hn);
        traj[(size_t)token * (STEPS * LAT) + step * LAT + latc] = hn;
      }
    }
  }
}

// ---------------- launcher ----------------
extern "C" void kernel_launch(void* const* d_in, const int* in_sizes, int n_in,
                              void* d_out, int out_size, void* d_ws, size_t ws_size,
                              hipStream_t stream) {
  const float* hs  = (const float*)d_in[0];
  const float* We1 = (const float*)d_in[2];
  const float* be1 = (const float*)d_in[3];
  const float* We2 = (const float*)d_in[4];
  const float* be2 = (const float*)d_in[5];
  const float* Wd1 = (const float*)d_in[6];
  const float* bd1 = (const float*)d_in[7];
  const float* Wd2 = (const float*)d_in[8];
  const float* bd2 = (const float*)d_in[9];
  const float* wih = (const float*)d_in[10];
  const float* whh = (const float*)d_in[11];
  const float* bih = (const float*)d_in[12];
  const float* bhh = (const float*)d_in[13];

  char* ws = (char*)d_ws;
  unsigned short* A0    = (unsigned short*)(ws + 0);          // 33,554,432 B
  unsigned short* We1b  = (unsigned short*)(ws + 33554432);   //  4,194,304
  unsigned short* We2b  = (unsigned short*)(ws + 37748736);   //  1,048,576
  unsigned short* Wd1b  = (unsigned short*)(ws + 38797312);   //  1,048,576
  unsigned short* Wd2b  = (unsigned short*)(ws + 39845888);   //  4,194,304
  unsigned short* Wg    = (unsigned short*)(ws + 44040192);   //  2,097,152
  float*          biasg = (float*)         (ws + 46137344);   //      8,192
  unsigned short* X1    = (unsigned short*)(ws + 46145536);   // 16,777,216
  unsigned short* Lb0   = (unsigned short*)(ws + 62922752);   //  8,388,608
  unsigned short* Lb1   = (unsigned short*)(ws + 71311360);   //  8,388,608
  unsigned short* X2    = A0;                                 // A0 dead after E1

  float* dec  = (float*)d_out;
  float* traj = (float*)d_out + DEC_ELEMS;

  // prep: fp32 -> bf16 casts + GRU weight packing
  k_cast<<<2048, 256, 0, stream>>>(hs,  A0,   TOKENS * HID / 4);
  k_cast<<<512,  256, 0, stream>>>(We1, We1b, LAT2 * HID / 4);
  k_cast<<<256,  256, 0, stream>>>(We2, We2b, LAT * LAT2 / 4);
  k_cast<<<256,  256, 0, stream>>>(Wd1, Wd1b, LAT2 * LAT / 4);
  k_cast<<<512,  256, 0, stream>>>(Wd2, Wd2b, HID * LAT2 / 4);
  k_gru_pack<<<GCOLS, 128, 0, stream>>>(wih, whh, bih, bhh, Wg, biasg);

  // encode (E1 back on 128^2: 512 blocks = 2/CU, full machine)
  gemm_bt<0><<<dim3(TOKENS / MWG, LAT2 / NWG), dim3(256), 0, stream>>>(
      A0, We1b, be1, HID, LAT2, nullptr, X1);
  gemm_bt<1><<<dim3(TOKENS / MWG, LAT / NWG), dim3(256), 0, stream>>>(
      X1, We2b, be2, LAT2, LAT, nullptr, Lb0);
  // GRU steps (double-buffered bf16 latent), 256^2 8-phase fused-gate kernel
  for (int s = 0; s < STEPS; ++s) {
    const unsigned short* lbi = (s & 1) ? Lb1 : Lb0;
    unsigned short*       lbo = (s & 1) ? Lb0 : Lb1;
    gemm256<3><<<256, 512, 0, stream>>>(lbi, Wg, biasg, LAT, GCOLS, 8,
                                        nullptr, lbo, lbi, traj, s);
  }
  // decode (after 8 steps latent is in Lb0)
  gemm_bt<0><<<dim3(TOKENS / MWG, LAT2 / NWG), dim3(256), 0, stream>>>(
      Lb0, Wd1b, bd1, LAT, LAT2, nullptr, X2);
  gemm256<2><<<256, 512, 0, stream>>>(X2, Wd2b, bd2, LAT2, HID, 8,
                                      dec, nullptr, nullptr, nullptr, 0);
}